// Round 3
// baseline (537.332 us; speedup 1.0000x reference)
//
#include <hip/hip_runtime.h>
#include <hip/hip_bf16.h>
#include <math.h>

#define NB 32
#define NN 1000
#define SS 200
#define DD 128
#define HH 8
#define DKK 16
#define FFD 512
#define NLAYER 3
#define LQ 802
#define LPAD 832           // padded key/query count (26 tiles of 32); pads are exact zeros
#define NPADK (LPAD - LQ)  // 30 pad keys -> contribute exactly 30*2^{-M} to denominator
#define MROWS (NB*LQ)      // 25664
#define NBLK64 (MROWS/64)  // 401 exactly
#define NQT 26             // key tiles of 32 (all full after padding)
#define NQT64 13           // query tiles of 64
#define HSTR 516           // H LDS stride (shorts): 2-bank step -> 2-way alias = free
#define TSTR 132           // T LDS stride (shorts): 2-bank step -> 2-way alias = free
#define QSCALE 0.3606737602f   // 0.25 * log2(e): softmax done in exp2 units

typedef __attribute__((ext_vector_type(8))) short short8;
typedef __attribute__((ext_vector_type(4))) short short4v;
typedef __attribute__((ext_vector_type(16))) float f32x16;
typedef __attribute__((ext_vector_type(2))) unsigned int uint2v;

static __device__ __forceinline__ unsigned short f2bf(float x) {
  union { float f; unsigned int u; } v; v.f = x;
  unsigned int r = v.u + 0x7fff + ((v.u >> 16) & 1);   // RNE
  return (unsigned short)(r >> 16);
}

// single-float bf16 convert in ONE VALU op (RNE, same as f2bf)
static __device__ __forceinline__ unsigned short f2bf1(float x) {
  unsigned int r;
  asm("v_cvt_pk_bf16_f32 %0, %1, 0" : "=v"(r) : "v"(x));
  return (unsigned short)r;
}

static __device__ __forceinline__ unsigned int cvtpk_bf16(float lo, float hi) {
  unsigned int r;
  asm("v_cvt_pk_bf16_f32 %0, %1, %2" : "=v"(r) : "v"(lo), "v"(hi));
  return r;
}

static __device__ __forceinline__ float max3f(float a, float b, float c) {
  float r;
  asm("v_max3_f32 %0, %1, %2, %3" : "=v"(r) : "v"(a), "v"(b), "v"(c));
  return r;
}

static __device__ __forceinline__ float exp2n(float x) {   // single v_exp_f32 (2^x)
  float r;
  asm("v_exp_f32 %0, %1" : "=v"(r) : "v"(x));
  return r;
}

// v_permlane32_swap_b32: exchanges one 32-lane half of A with the complementary half
// of B, returns both post-swap registers. Operand direction is probed at runtime.
static __device__ __forceinline__ uint2v pls(unsigned int a, unsigned int b) {
  return __builtin_amdgcn_permlane32_swap(a, b, false, false);
}
static __device__ __forceinline__ unsigned int fu(float x){ return __float_as_uint(x); }
static __device__ __forceinline__ float uf(unsigned int x){ return __uint_as_float(x); }

// ---------------- weight transpose+convert: W[k][n] fp32 -> Wt[n][k] bf16 ----------------
#define WCH 196608         // per-layer: 49152+16384+65536+65536
__global__ __launch_bounds__(256) void k_wconv(const float* __restrict__ Wq, const float* __restrict__ Wk,
                       const float* __restrict__ Wv, const float* __restrict__ Wo,
                       const float* __restrict__ W1, const float* __restrict__ W2,
                       unsigned short* __restrict__ WtQKV, unsigned short* __restrict__ Wot,
                       unsigned short* __restrict__ W1t, unsigned short* __restrict__ W2t) {
  int e = blockIdx.x*256 + threadIdx.x;
  if (e >= 3*WCH) return;
  int layer = e / WCH, r = e - layer*WCH;
  if (r < 49152) {
    int n = r >> 7, k = r & 127;
    int sect = n >> 7, nn = n & 127;
    const float* W = (sect == 0) ? Wq : (sect == 1) ? Wk : Wv;
    WtQKV[layer*49152 + r] = f2bf1(W[layer*16384 + k*128 + nn]);
  } else if (r < 65536) {
    int r2 = r - 49152;
    int n = r2 >> 7, k = r2 & 127;
    Wot[layer*16384 + r2] = f2bf1(Wo[layer*16384 + k*128 + n]);
  } else if (r < 131072) {
    int r2 = r - 65536;
    int n = r2 >> 7, k = r2 & 127;
    W1t[layer*65536 + r2] = f2bf1(W1[layer*65536 + k*512 + n]);
  } else {
    int r2 = r - 131072;
    int n = r2 >> 9, k = r2 & 511;
    W2t[layer*65536 + r2] = f2bf1(W2[layer*65536 + k*128 + n]);
  }
}

// ---------------- unselect + pos (inverse map), ballot-scan ----------------
__global__ __launch_bounds__(1024) void k_unselect(const int* __restrict__ sel,
                                                   int* __restrict__ unselect,
                                                   int* __restrict__ pos) {
  int b = blockIdx.x;
  int n = threadIdx.x;
  __shared__ unsigned char fl[1024];
  __shared__ int wsum[16];
  fl[n] = (n < NN) ? 1 : 0;
  __syncthreads();
  if (n < SS) fl[sel[b*SS + n]] = 0;
  __syncthreads();
  int flag = fl[n];
  unsigned long long m = __ballot(flag);
  int lane = n & 63, w = n >> 6;
  int pre = __popcll(m & ((1ULL << lane) - 1ULL));
  if (lane == 63) wsum[w] = pre + flag;
  __syncthreads();
  int off = 0;
  #pragma unroll
  for (int i = 0; i < 16; ++i) off += (i < w) ? wsum[i] : 0;
  if (n < NN) {
    if (flag) {
      int j = off + pre;
      unselect[b*800 + j] = n;
      pos[b*NN + n] = j + 1;
    } else {
      pos[b*NN + n] = -1;
    }
  }
}

// ---------------- X ends: rows 0 and LQ-1 (matvec) ----------------
__global__ __launch_bounds__(128) void k_embed_ends(const float* __restrict__ data,
                       const int* __restrict__ sel,
                       const float* __restrict__ Wfirst, const float* __restrict__ bfirst,
                       const float* __restrict__ Wlast, const float* __restrict__ blast,
                       float* __restrict__ X, unsigned short* __restrict__ Xbf) {
  int which = blockIdx.x, b = blockIdx.y, d = threadIdx.x;
  int l = (which == 0) ? 0 : LQ-1;
  __shared__ float xr[DD];
  int src = sel[b*SS + (which == 0 ? 0 : SS-1)];
  const float* W    = (which == 0) ? Wfirst : Wlast;
  const float* bias = (which == 0) ? bfirst : blast;
  xr[d] = data[((size_t)b*NN + src)*DD + d];
  __syncthreads();
  float acc = bias[d];
  #pragma unroll 4
  for (int k = 0; k < DD; ++k) acc += xr[k] * W[k*DD + d];
  size_t off = ((size_t)(b*LQ + l))*DD + d;
  X[off] = acc;
  Xbf[off] = f2bf1(acc);
}

// ---------------- X middle: gather rows, float4 ----------------
__global__ __launch_bounds__(256) void k_embed_mid(const float* __restrict__ data,
                       const int* __restrict__ unselect,
                       float* __restrict__ X, unsigned short* __restrict__ Xbf) {
  int e = blockIdx.x*256 + threadIdx.x;      // 819200 total
  int r = e >> 5;                            // 0..25599
  int c4 = (e & 31) * 4;
  int b = r / 800, j = r - b*800;
  int nidx = unselect[r];
  const float4 v = *(const float4*)&data[((size_t)b*NN + nidx)*DD + c4];
  size_t off = ((size_t)(b*LQ + 1 + j))*DD + c4;
  *(float4*)&X[off] = v;
  unsigned int lo = cvtpk_bf16(v.x, v.y);
  unsigned int hi = cvtpk_bf16(v.z, v.w);
  unsigned long long pk8 = ((unsigned long long)hi << 32) | (unsigned long long)lo;
  *(unsigned long long*)&Xbf[off] = pk8;
}

// ---------------- MFMA QKV: C[M x 384] = Xbf @ [Wq|Wk|Wv]; row-major Q/K/V [bh][LPAD][dk] ----------------
// Q is pre-scaled by 0.25*log2e so attention softmax runs in exp2 units.
__global__ __launch_bounds__(256) void k_qkv_mfma(const unsigned short* __restrict__ Xbf,
                       const unsigned short* __restrict__ Wt,   // [384][128]
                       unsigned short* __restrict__ Qb, unsigned short* __restrict__ Kb,
                       unsigned short* __restrict__ Vb) {
  int row0 = blockIdx.x * 64;
  int t = threadIdx.x, wave = t >> 6, lane = t & 63;
  int col = lane & 31, half = lane >> 5;
  // batch-split trick: a 64-row block crosses at most one batch boundary
  int b0 = row0 / LQ;
  int l00 = row0 - b0*LQ;
  int split = LQ - l00;          // ml < split -> batch b0 at row l00+ml; else b0+1 at ml-split
  short8 a[2][8];
  const unsigned short* xb = Xbf + (size_t)(row0 + col)*DD + half*8;
  #pragma unroll
  for (int mi = 0; mi < 2; ++mi)
    #pragma unroll
    for (int s = 0; s < 8; ++s)
      a[mi][s] = *(const short8*)(xb + (size_t)mi*32*DD + s*16);
  #pragma unroll
  for (int nn = 0; nn < 3; ++nn) {
    int ni = wave*3 + nn;
    short8 bfr[8];
    const unsigned short* wb = Wt + (size_t)(ni*32 + col)*DD + half*8;
    #pragma unroll
    for (int s = 0; s < 8; ++s) bfr[s] = *(const short8*)(wb + s*16);
    f32x16 acc0 = {0.f,0.f,0.f,0.f,0.f,0.f,0.f,0.f,0.f,0.f,0.f,0.f,0.f,0.f,0.f,0.f};
    f32x16 acc1 = {0.f,0.f,0.f,0.f,0.f,0.f,0.f,0.f,0.f,0.f,0.f,0.f,0.f,0.f,0.f,0.f};
    #pragma unroll
    for (int s = 0; s < 8; ++s) {
      acc0 = __builtin_amdgcn_mfma_f32_32x32x16_bf16(a[0][s], bfr[s], acc0, 0, 0, 0);
      acc1 = __builtin_amdgcn_mfma_f32_32x32x16_bf16(a[1][s], bfr[s], acc1, 0, 0, 0);
    }
    int n = ni*32 + col;
    int sect = n >> 7, nc = n & 127;
    int h = nc >> 4, d = nc & 15;
    #pragma unroll
    for (int mi = 0; mi < 2; ++mi) {
      const f32x16& acc = mi ? acc1 : acc0;
      #pragma unroll
      for (int r = 0; r < 16; ++r) {
        int ml = mi*32 + (r&3) + 8*(r>>2) + 4*half;
        int over = (ml >= split);
        int b_ = b0 + over;
        int l  = over ? (ml - split) : (l00 + ml);
        size_t bh = (size_t)(b_*HH + h);
        float v = acc[r];
        if (sect == 0)      Qb[(bh*LPAD + l)*DKK + d] = f2bf1(v * QSCALE);
        else if (sect == 1) Kb[(bh*LPAD + l)*DKK + d] = f2bf1(v);
        else                Vb[(bh*LPAD + l)*DKK + d] = f2bf1(v);
      }
    }
  }
}

// ---------------- V transpose (LDS-tiled) + zero pads of Vt and Kb ----------------
__global__ __launch_bounds__(256) void k_vt(const unsigned short* __restrict__ Vb,  // [bh][LPAD][16]
                                            unsigned short* __restrict__ Vt,        // [bh][16][LPAD]
                                            unsigned short* __restrict__ Kb) {
  __shared__ unsigned short Lt[16][72];
  int l0 = blockIdx.x * 64;                 // 13 tiles cover 832
  int bh = blockIdx.y;
  int t = threadIdx.x;
  int l = t >> 2, d4 = (t & 3) * 4;
  ushort4 v = {0,0,0,0};
  if (l0 + l < LQ) v = *(const ushort4*)&Vb[((size_t)bh*LPAD + l0 + l)*DKK + d4];
  Lt[d4+0][l] = v.x; Lt[d4+1][l] = v.y; Lt[d4+2][l] = v.z; Lt[d4+3][l] = v.w;
  __syncthreads();
  int dk = t >> 4, lq = (t & 15)*4;
  ushort4 o;
  o.x = Lt[dk][lq]; o.y = Lt[dk][lq+1]; o.z = Lt[dk][lq+2]; o.w = Lt[dk][lq+3];
  *(ushort4*)&Vt[((size_t)bh*DKK + dk)*LPAD + l0 + lq] = o;
  if (blockIdx.x == 12 && t < 240)          // zero Kb pad rows (30 rows * 16 dk = 240 uints)
    ((unsigned int*)&Kb[((size_t)bh*LPAD + LQ)*DKK])[t] = 0u;
}

// ---------------- flash attention, 64 queries/block, S^T = K·Q^T, padded keys ----------------
// 4 waves split key tiles, 2 independent q-chains/wave (2x ILP on the serial softmax path).
// exp2-unit softmax, v_max3 tree, defer-rescale, cvt_pk pack. Cross-half exchange now via
// v_permlane32_swap_b32 (VALU pipe, both outputs used) instead of ds_bpermute-routed shfl;
// operand direction resolved by a one-time wave-uniform probe (loop-unswitched).
__global__ __launch_bounds__(256) void k_attn3(const unsigned short* __restrict__ Q,
                       const unsigned short* __restrict__ K,
                       const unsigned short* __restrict__ Vt,
                       unsigned short* __restrict__ Obf) {
  int bid = blockIdx.x;
  int g = bid & 7, i = bid >> 3;            // XCD swizzle
  int bhg = i / NQT64, qt = i - bhg*NQT64;
  int bh = bhg*8 + g;
  int b = bh >> 3, h = bh & 7;
  int q0 = qt*64;
  size_t bhL = (size_t)bh * LPAD;
  int t = threadIdx.x;
  int wave = t >> 6, lane = t & 63;
  int col = lane & 31;
  int half = lane >> 5;

  __shared__ float mw[2][4][32];
  __shared__ float sw[2][4][32];
  __shared__ float sfin[2][32];
  __shared__ float ored[2][4][16][32];      // 16 KB
  __shared__ float osum[2][32][17];

  // direction probe: case1 <=> new D.lo = S.hi (i.e. pls(D,S) moves S's high half into D's low half)
  uint2v pr = pls(1000u + (unsigned)lane, 2000u + (unsigned)lane);
  bool case1 = (__builtin_amdgcn_readfirstlane((int)pr.x) >= 2000);

  int q0c = q0 + col;      if (q0c > LQ-1) q0c = LQ-1;
  int q1c = q0 + 32 + col; if (q1c > LQ-1) q1c = LQ-1;
  short8 bQ0 = *(const short8*)&Q[(bhL + q0c)*DKK + half*8];
  short8 bQ1 = *(const short8*)&Q[(bhL + q1c)*DKK + half*8];

  f32x16 oacc0 = {0.f,0.f,0.f,0.f,0.f,0.f,0.f,0.f,0.f,0.f,0.f,0.f,0.f,0.f,0.f,0.f};
  f32x16 oacc1 = oacc0;
  float runm0 = -INFINITY, runs0 = 0.f;
  float runm1 = -INFINITY, runs1 = 0.f;

  for (int kt = wave; kt < NQT; kt += 4) {
    int key0 = kt*32;
    short8 aK = *(const short8*)&K[(bhL + key0 + col)*DKK + half*8];
    short8 aV0 = {0,0,0,0,0,0,0,0};
    short8 aV1 = {0,0,0,0,0,0,0,0};
    if (col < 16) {
      const unsigned short* vp = &Vt[((size_t)bh*DKK + col)*LPAD + key0 + half*8];
      aV0 = *(const short8*)vp;
      aV1 = *(const short8*)(vp + 16);
    }

    auto process = [&](const short8& bQ, f32x16& oacc, float& runm, float& runs) {
      f32x16 c = {0.f,0.f,0.f,0.f,0.f,0.f,0.f,0.f,0.f,0.f,0.f,0.f,0.f,0.f,0.f,0.f};
      c = __builtin_amdgcn_mfma_f32_32x32x16_bf16(aK, bQ, c, 0, 0, 0);
      // row max via v_max3 tree (8 ops, shallow)
      float m0 = max3f(c[0],  c[1],  c[2]);
      float m1 = max3f(c[3],  c[4],  c[5]);
      float m2 = max3f(c[6],  c[7],  c[8]);
      float m3 = max3f(c[9],  c[10], c[11]);
      float m4 = max3f(c[12], c[13], c[14]);
      float tm = fmaxf(max3f(m0, m1, m2), max3f(m3, m4, c[15]));
      {   // half-pair max, direction-agnostic (own value included explicitly)
        uint2v r = pls(fu(tm), fu(tm));
        tm = max3f(tm, uf(r.x), uf(r.y));
      }
      if (!__all(tm <= runm + 11.0f)) {         // defer-rescale: p bounded by 2^11
        float mnew = fmaxf(runm, tm);
        float sc = exp2n(runm - mnew);
        runs *= sc;
        #pragma unroll
        for (int r = 0; r < 8; ++r) oacc[r] *= sc;
        runm = mnew;
      }
      float p[16];
      #pragma unroll
      for (int r = 0; r < 16; ++r) p[r] = exp2n(c[r] - runm);
      float s01 = p[0]+p[1],  s23 = p[2]+p[3],   s45 = p[4]+p[5],   s67 = p[6]+p[7];
      float s89 = p[8]+p[9],  sab = p[10]+p[11], scd = p[12]+p[13], sef = p[14]+p[15];
      runs += ((s01+s23)+(s45+s67)) + ((s89+sab)+(scd+sef));
      unsigned int pk[8];
      #pragma unroll
      for (int j = 0; j < 8; ++j) pk[j] = cvtpk_bf16(p[2*j], p[2*j+1]);
      // build MFMA A-fragments: lo lanes keep pk[0..1]/pk[4..5] own, get partner pk[2..3]/pk[6..7];
      // hi lanes symmetric. One permlane32_swap yields BOTH words (loop-unswitched on case1).
      unsigned int fAx, fAy, fAz, fAw, fBx, fBy, fBz, fBw;
      if (case1) {
        uint2v r0 = pls(pk[2], pk[0]); fAz = r0.x; fAx = r0.y;
        uint2v r1 = pls(pk[3], pk[1]); fAw = r1.x; fAy = r1.y;
        uint2v r2 = pls(pk[6], pk[4]); fBz = r2.x; fBx = r2.y;
        uint2v r3 = pls(pk[7], pk[5]); fBw = r3.x; fBy = r3.y;
      } else {
        uint2v r0 = pls(pk[0], pk[2]); fAx = r0.x; fAz = r0.y;
        uint2v r1 = pls(pk[1], pk[3]); fAy = r1.x; fAw = r1.y;
        uint2v r2 = pls(pk[4], pk[6]); fBx = r2.x; fBz = r2.y;
        uint2v r3 = pls(pk[5], pk[7]); fBy = r3.x; fBw = r3.y;
      }
      union { unsigned int u[4]; short8 s8; } fA, fB;
      fA.u[0] = fAx; fA.u[1] = fAy; fA.u[2] = fAz; fA.u[3] = fAw;
      fB.u[0] = fBx; fB.u[1] = fBy; fB.u[2] = fBz; fB.u[3] = fBw;
      oacc = __builtin_amdgcn_mfma_f32_32x32x16_bf16(aV0, fA.s8, oacc, 0, 0, 0);
      oacc = __builtin_amdgcn_mfma_f32_32x32x16_bf16(aV1, fB.s8, oacc, 0, 0, 0);
    };
    process(bQ0, oacc0, runm0, runs0);
    process(bQ1, oacc1, runm1, runs1);
  }

  // ---- merge halves, then waves (all in exp2 units) ----
  float m2v[2], fsv[2];
  #pragma unroll
  for (int u = 0; u < 2; ++u) {
    float runm = u ? runm1 : runm0;
    float runs = u ? runs1 : runs0;
    uint2v rm = pls(fu(runm), fu(runm));
    float m2 = max3f(runm, uf(rm.x), uf(rm.y));     // pair max, direction-agnostic
    float fself = exp2n(runm - m2);
    float e = runs * fself;                          // own exp-weighted sum
    uint2v re = pls(fu(e), fu(e));
    float s2 = uf(re.x) + uf(re.y);                  // own + partner (half-swap pair sum)
    if (half == 0) { mw[u][wave][col] = m2; sw[u][wave][col] = s2; }
    m2v[u] = m2; fsv[u] = fself;
  }
  __syncthreads();
  #pragma unroll
  for (int u = 0; u < 2; ++u) {
    float M = fmaxf(fmaxf(mw[u][0][col], mw[u][1][col]), fmaxf(mw[u][2][col], mw[u][3][col]));
    float S = sw[u][0][col]*exp2n(mw[u][0][col]-M) + sw[u][1][col]*exp2n(mw[u][1][col]-M)
            + sw[u][2][col]*exp2n(mw[u][2][col]-M) + sw[u][3][col]*exp2n(mw[u][3][col]-M);
    float fw = exp2n(m2v[u] - M) * fsv[u];
    const f32x16& oacc = u ? oacc1 : oacc0;
    #pragma unroll
    for (int r = 0; r < 8; ++r) {
      int dv = (r&3) + 8*(r>>2) + 4*half;
      ored[u][wave][dv][col] = oacc[r] * fw;
    }
    if (wave == 0 && half == 0)
      sfin[u][col] = S - (float)NPADK * exp2n(-M);   // remove exact pad mass
  }
  __syncthreads();
  {
    int qq = t & 31, dv0 = t >> 5;
    #pragma unroll
    for (int u = 0; u < 2; ++u)
      #pragma unroll
      for (int k = 0; k < 2; ++k) {
        int dv = dv0 + 8*k;
        osum[u][qq][dv] = ored[u][0][dv][qq] + ored[u][1][dv][qq]
                        + ored[u][2][dv][qq] + ored[u][3][dv][qq];
      }
  }
  __syncthreads();
  {
    int qs = t >> 3, c2 = (t & 7)*2;
    #pragma unroll
    for (int u = 0; u < 2; ++u) {
      int q = q0 + u*32 + qs;
      if (q < LQ) {
        float invS = 1.f / sfin[u][qs];
        unsigned int pkv = cvtpk_bf16(osum[u][qs][c2] * invS, osum[u][qs][c2+1] * invS);
        *(unsigned int*)&Obf[((size_t)(b*LQ + q))*DD + h*DKK + c2] = pkv;
      }
    }
  }
}

// ---------------- fused proj + FF: X = out1 + ff(out1), out1 = X + Obf@Wo + bo ----------------
__global__ __launch_bounds__(256) void k_pff(const unsigned short* __restrict__ Obf,
        const unsigned short* __restrict__ Wot, const float* __restrict__ bo,
        const unsigned short* __restrict__ W1t, const float* __restrict__ b1,
        const unsigned short* __restrict__ W2t, const float* __restrict__ b2,
        float* __restrict__ X, unsigned short* __restrict__ Xbf) {
  __shared__ __align__(16) unsigned short LDSU[64 * HSTR];   // 66048 B, union T/Hs
  unsigned short* T  = LDSU;
  unsigned short* Hs = LDSU;
  int row0 = blockIdx.x * 64;
  int t = threadIdx.x, wave = t >> 6, lane = t & 63;
  int col = lane & 31, half = lane >> 5;
  int n = wave*32 + col;
  float res[2][16];
  {
    short8 a[2][8];
    const unsigned short* ob = Obf + (size_t)(row0 + col)*DD + half*8;
    #pragma unroll
    for (int mi = 0; mi < 2; ++mi)
      #pragma unroll
      for (int s = 0; s < 8; ++s)
        a[mi][s] = *(const short8*)(ob + (size_t)mi*32*DD + s*16);
    short8 bfr[8];
    const unsigned short* wb = Wot + (size_t)n*DD + half*8;
    #pragma unroll
    for (int s = 0; s < 8; ++s) bfr[s] = *(const short8*)(wb + s*16);
    f32x16 acc0 = {0.f,0.f,0.f,0.f,0.f,0.f,0.f,0.f,0.f,0.f,0.f,0.f,0.f,0.f,0.f,0.f};
    f32x16 acc1 = acc0;
    #pragma unroll
    for (int s = 0; s < 8; ++s) {
      acc0 = __builtin_amdgcn_mfma_f32_32x32x16_bf16(a[0][s], bfr[s], acc0, 0, 0, 0);
      acc1 = __builtin_amdgcn_mfma_f32_32x32x16_bf16(a[1][s], bfr[s], acc1, 0, 0, 0);
    }
    float bv = bo[n];
    #pragma unroll
    for (int mi = 0; mi < 2; ++mi) {
      const f32x16& acc = mi ? acc1 : acc0;
      #pragma unroll
      for (int r = 0; r < 16; ++r) {
        int ml = mi*32 + (r&3) + 8*(r>>2) + 4*half;
        size_t off = (size_t)(row0 + ml)*DD + n;
        res[mi][r] = X[off] + acc[r] + bv;
        T[ml*TSTR + n] = f2bf1(res[mi][r]);
      }
    }
  }
  __syncthreads();
  short8 aF[2][8];
  #pragma unroll
  for (int mi = 0; mi < 2; ++mi)
    #pragma unroll
    for (int s = 0; s < 8; ++s) {
      const unsigned short* tp = &T[(mi*32 + col)*TSTR + half*8 + s*16];
      union { short4v h[2]; short8 v; } u;
      u.h[0] = *(const short4v*)tp;
      u.h[1] = *(const short4v*)(tp + 4);
      aF[mi][s] = u.v;
    }
  __syncthreads();
  #pragma unroll
  for (int nn = 0; nn < 4; ++nn) {
    int ni = wave*4 + nn;
    short8 bfr[8];
    const unsigned short* wb = W1t + (size_t)(ni*32 + col)*DD + half*8;
    #pragma unroll
    for (int s = 0; s < 8; ++s) bfr[s] = *(const short8*)(wb + s*16);
    f32x16 acc0 = {0.f,0.f,0.f,0.f,0.f,0.f,0.f,0.f,0.f,0.f,0.f,0.f,0.f,0.f,0.f,0.f};
    f32x16 acc1 = acc0;
    #pragma unroll
    for (int s = 0; s < 8; ++s) {
      acc0 = __builtin_amdgcn_mfma_f32_32x32x16_bf16(aF[0][s], bfr[s], acc0, 0, 0, 0);
      acc1 = __builtin_amdgcn_mfma_f32_32x32x16_bf16(aF[1][s], bfr[s], acc1, 0, 0, 0);
    }
    int nf = ni*32 + col;
    float bv = b1[nf];
    #pragma unroll
    for (int mi = 0; mi < 2; ++mi) {
      const f32x16& acc = mi ? acc1 : acc0;
      #pragma unroll
      for (int r = 0; r < 16; ++r) {
        int ml = mi*32 + (r&3) + 8*(r>>2) + 4*half;
        Hs[ml*HSTR + nf] = f2bf1(fmaxf(acc[r] + bv, 0.f));
      }
    }
  }
  __syncthreads();
  f32x16 acc0 = {0.f,0.f,0.f,0.f,0.f,0.f,0.f,0.f,0.f,0.f,0.f,0.f,0.f,0.f,0.f,0.f};
  f32x16 acc1 = acc0;
  const unsigned short* w2b = W2t + (size_t)n*FFD + half*8;
  #pragma unroll 4
  for (int s = 0; s < 32; ++s) {
    int ko = s*16 + half*8;
    union { short4v h[2]; short8 v; } h0, h1;
    const unsigned short* hp0 = &Hs[col*HSTR + ko];
    const unsigned short* hp1 = &Hs[(32 + col)*HSTR + ko];
    h0.h[0] = *(const short4v*)hp0;  h0.h[1] = *(const short4v*)(hp0 + 4);
    h1.h[0] = *(const short4v*)hp1;  h1.h[1] = *(const short4v*)(hp1 + 4);
    short8 bfr = *(const short8*)(w2b + s*16);
    acc0 = __builtin_amdgcn_mfma_f32_32x32x16_bf16(h0.v, bfr, acc0, 0, 0, 0);
    acc1 = __builtin_amdgcn_mfma_f32_32x32x16_bf16(h1.v, bfr, acc1, 0, 0, 0);
  }
  float bv = b2[n];
  #pragma unroll
  for (int mi = 0; mi < 2; ++mi) {
    const f32x16& acc = mi ? acc1 : acc0;
    #pragma unroll
    for (int r = 0; r < 16; ++r) {
      int ml = mi*32 + (r&3) + 8*(r>>2) + 4*half;
      size_t off = (size_t)(row0 + ml)*DD + n;
      float v = res[mi][r] + acc[r] + bv;
      X[off] = v;
      Xbf[off] = f2bf1(v);
    }
  }
}

// ---------------- logits: one wave per row ----------------
__global__ __launch_bounds__(256) void k_logits(const float* __restrict__ X,
                        const float* __restrict__ Wfin, const float* __restrict__ bfin,
                        float* __restrict__ logits) {
  int t = threadIdx.x, wave = t >> 6, lane = t & 63;
  int row = blockIdx.x*4 + wave;            // 6416*4 = 25664 exact
  float2 xv = *(const float2*)&X[(size_t)row*DD + lane*2];
  float2 wv = *(const float2*)&Wfin[lane*2];
  float v = xv.x*wv.x + xv.y*wv.y;
  #pragma unroll
  for (int off = 32; off > 0; off >>= 1) v += __shfl_down(v, off);
  if (lane == 0) logits[row] = v + bfin[0];
}

// ---------------- bias add, softmax, epsilon, scatter ----------------
__global__ __launch_bounds__(256) void k_final(const float* __restrict__ logits,
                       const float* __restrict__ AB, const int* __restrict__ sel,
                       const int* __restrict__ unselect, const int* __restrict__ pos,
                       float* __restrict__ out) {
  int b = blockIdx.x, t = threadIdx.x;
  __shared__ float sl[800];
  __shared__ float red[256];
  int lastsel = sel[b*SS + SS-1];
  const float* abrow = AB + ((size_t)b*NN + lastsel)*NN;
  for (int j = t; j < 800; j += 256)
    sl[j] = logits[b*LQ + j + 1] + abrow[unselect[b*800 + j]];
  __syncthreads();
  float lm = -INFINITY;
  for (int j = t; j < 800; j += 256) lm = fmaxf(lm, sl[j]);
  red[t] = lm;
  __syncthreads();
  for (int s = 128; s > 0; s >>= 1) {
    if (t < s) red[t] = fmaxf(red[t], red[t+s]);
    __syncthreads();
  }
  float m = red[0];
  __syncthreads();
  float ls = 0.f;
  for (int j = t; j < 800; j += 256) ls += __expf(sl[j] - m);
  red[t] = ls;
  __syncthreads();
  for (int s = 128; s > 0; s >>= 1) {
    if (t < s) red[t] += red[t+s];
    __syncthreads();
  }
  float inv = 1.f / red[0];
  for (int n = t; n < NN; n += 256) {
    int p1 = pos[b*NN + n];
    float v = -2.0f;
    if (p1 >= 0) {
      float p = __expf(sl[p1-1] - m) * inv;
      if (p <= 1e-5f) p += 1e-7f;
      v = p;
    }
    out[(size_t)b*NN + n] = v;
  }
}

extern "C" void kernel_launch(void* const* d_in, const int* in_sizes, int n_in,
                              void* d_out, int out_size, void* d_ws, size_t ws_size,
                              hipStream_t stream) {
  const float* data   = (const float*)d_in[0];
  const float* AB     = (const float*)d_in[1];
  const float* Wfirst = (const float*)d_in[2];
  const float* bfirst = (const float*)d_in[3];
  const float* Wlast  = (const float*)d_in[4];
  const float* blast  = (const float*)d_in[5];
  const float* Wq     = (const float*)d_in[6];
  const float* Wk     = (const float*)d_in[7];
  const float* Wv     = (const float*)d_in[8];
  const float* Wo     = (const float*)d_in[9];
  const float* bo     = (const float*)d_in[10];
  const float* W1     = (const float*)d_in[11];
  const float* b1     = (const float*)d_in[12];
  const float* W2     = (const float*)d_in[13];
  const float* b2     = (const float*)d_in[14];
  const float* Wfin   = (const float*)d_in[15];
  const float* bfin   = (const float*)d_in[16];
  const int*   sel    = (const int*)d_in[17];
  float* out = (float*)d_out;
  (void)in_sizes; (void)n_in; (void)out_size; (void)ws_size;

  char* ws = (char*)d_ws;
  const size_t NELT = (size_t)MROWS * DD;        // 3,284,992
  const size_t KVELT = (size_t)NB*HH*LPAD*DKK;   // 3,407,872
  int*   UNSEL = (int*)ws;
  int*   POS   = (int*)(ws + 102400);
  float* X     = (float*)(ws + 230400);
  unsigned short* Xbf = (unsigned short*)(X + NELT);
  unsigned short* Ob  = Xbf + NELT;
  unsigned short* Qb  = Ob + NELT;
  unsigned short* Kb  = Qb + KVELT;
  unsigned short* Vb  = Kb + KVELT;
  unsigned short* Vt  = Vb + KVELT;
  unsigned short* WtQKV = Vt + KVELT;
  unsigned short* Wot = WtQKV + (size_t)NLAYER*384*128;
  unsigned short* W1t = Wot + (size_t)NLAYER*128*128;
  unsigned short* W2t = W1t + (size_t)NLAYER*512*128;
  float* LOG = (float*)(W2t + (size_t)NLAYER*128*512);

  k_wconv<<<(3*WCH + 255)/256, 256, 0, stream>>>(Wq, Wk, Wv, Wo, W1, W2, WtQKV, Wot, W1t, W2t);
  k_unselect<<<NB, 1024, 0, stream>>>(sel, UNSEL, POS);
  k_embed_ends<<<dim3(2, NB), 128, 0, stream>>>(data, sel, Wfirst, bfirst, Wlast, blast, X, Xbf);
  k_embed_mid<<<3200, 256, 0, stream>>>(data, UNSEL, X, Xbf);
  for (int i = 0; i < NLAYER; ++i) {
    k_qkv_mfma<<<NBLK64, 256, 0, stream>>>(Xbf, WtQKV + (size_t)i*384*128, Qb, Kb, Vb);
    k_vt<<<dim3(13, NB*HH), 256, 0, stream>>>(Vb, Vt, Kb);
    k_attn3<<<NQT64*HH*NB, 256, 0, stream>>>(Qb, Kb, Vt, Ob);
    k_pff<<<NBLK64, 256, 0, stream>>>(Ob, Wot + (size_t)i*128*128, bo + (size_t)i*DD,
                                      W1t + (size_t)i*512*128, b1 + (size_t)i*FFD,
                                      W2t + (size_t)i*128*512, b2 + (size_t)i*DD, X, Xbf);
  }
  k_logits<<<MROWS/4, 256, 0, stream>>>(X, Wfin, bfin, LOG);
  k_final<<<NB, 256, 0, stream>>>(LOG, AB, sel, UNSEL, POS, out);
}

// Round 4
// 528.483 us; speedup vs baseline: 1.0167x; 1.0167x over previous
//
#include <hip/hip_runtime.h>
#include <hip/hip_bf16.h>
#include <math.h>

#define NB 32
#define NN 1000
#define SS 200
#define DD 128
#define HH 8
#define DKK 16
#define FFD 512
#define NLAYER 3
#define LQ 802
#define LPAD 832           // padded key/query count (26 tiles of 32); pads are exact zeros
#define NPADK (LPAD - LQ)  // 30 pad keys -> contribute exactly 30*2^{-M} to denominator
#define MROWS (NB*LQ)      // 25664
#define NBLK64 (MROWS/64)  // 401 exactly
#define NQT 26             // key tiles of 32 (all full after padding)
#define NQT64 13           // query tiles of 64
#define HSTR 516           // H LDS stride (shorts): 2-bank step -> 2-way alias = free
#define TSTR 132           // T LDS stride (shorts): 2-bank step -> 2-way alias = free
#define QSCALE 0.3606737602f   // 0.25 * log2(e): softmax done in exp2 units

typedef __attribute__((ext_vector_type(8))) short short8;
typedef __attribute__((ext_vector_type(4))) short short4v;
typedef __attribute__((ext_vector_type(16))) float f32x16;
typedef __attribute__((ext_vector_type(2))) unsigned int uint2v;

static __device__ __forceinline__ unsigned short f2bf(float x) {
  union { float f; unsigned int u; } v; v.f = x;
  unsigned int r = v.u + 0x7fff + ((v.u >> 16) & 1);   // RNE
  return (unsigned short)(r >> 16);
}

// single-float bf16 convert in ONE VALU op (RNE, same as f2bf)
static __device__ __forceinline__ unsigned short f2bf1(float x) {
  unsigned int r;
  asm("v_cvt_pk_bf16_f32 %0, %1, 0" : "=v"(r) : "v"(x));
  return (unsigned short)r;
}

static __device__ __forceinline__ unsigned int cvtpk_bf16(float lo, float hi) {
  unsigned int r;
  asm("v_cvt_pk_bf16_f32 %0, %1, %2" : "=v"(r) : "v"(lo), "v"(hi));
  return r;
}

static __device__ __forceinline__ float max3f(float a, float b, float c) {
  float r;
  asm("v_max3_f32 %0, %1, %2, %3" : "=v"(r) : "v"(a), "v"(b), "v"(c));
  return r;
}

static __device__ __forceinline__ float exp2n(float x) {   // single v_exp_f32 (2^x)
  float r;
  asm("v_exp_f32 %0, %1" : "=v"(r) : "v"(x));
  return r;
}

// v_permlane32_swap_b32: exchanges one 32-lane half of A with the complementary half
// of B, returns both post-swap registers. Operand direction is probed at runtime.
static __device__ __forceinline__ uint2v pls(unsigned int a, unsigned int b) {
  return __builtin_amdgcn_permlane32_swap(a, b, false, false);
}
static __device__ __forceinline__ unsigned int fu(float x){ return __float_as_uint(x); }
static __device__ __forceinline__ float uf(unsigned int x){ return __uint_as_float(x); }

// ---------------- weight transpose+convert: W[k][n] fp32 -> Wt[n][k] bf16 ----------------
#define WCH 196608         // per-layer: 49152+16384+65536+65536
__global__ __launch_bounds__(256) void k_wconv(const float* __restrict__ Wq, const float* __restrict__ Wk,
                       const float* __restrict__ Wv, const float* __restrict__ Wo,
                       const float* __restrict__ W1, const float* __restrict__ W2,
                       unsigned short* __restrict__ WtQKV, unsigned short* __restrict__ Wot,
                       unsigned short* __restrict__ W1t, unsigned short* __restrict__ W2t) {
  int e = blockIdx.x*256 + threadIdx.x;
  if (e >= 3*WCH) return;
  int layer = e / WCH, r = e - layer*WCH;
  if (r < 49152) {
    int n = r >> 7, k = r & 127;
    int sect = n >> 7, nn = n & 127;
    const float* W = (sect == 0) ? Wq : (sect == 1) ? Wk : Wv;
    WtQKV[layer*49152 + r] = f2bf1(W[layer*16384 + k*128 + nn]);
  } else if (r < 65536) {
    int r2 = r - 49152;
    int n = r2 >> 7, k = r2 & 127;
    Wot[layer*16384 + r2] = f2bf1(Wo[layer*16384 + k*128 + n]);
  } else if (r < 131072) {
    int r2 = r - 65536;
    int n = r2 >> 7, k = r2 & 127;
    W1t[layer*65536 + r2] = f2bf1(W1[layer*65536 + k*512 + n]);
  } else {
    int r2 = r - 131072;
    int n = r2 >> 9, k = r2 & 511;
    W2t[layer*65536 + r2] = f2bf1(W2[layer*65536 + k*128 + n]);
  }
}

// ---------------- unselect + pos (inverse map), ballot-scan ----------------
__global__ __launch_bounds__(1024) void k_unselect(const int* __restrict__ sel,
                                                   int* __restrict__ unselect,
                                                   int* __restrict__ pos) {
  int b = blockIdx.x;
  int n = threadIdx.x;
  __shared__ unsigned char fl[1024];
  __shared__ int wsum[16];
  fl[n] = (n < NN) ? 1 : 0;
  __syncthreads();
  if (n < SS) fl[sel[b*SS + n]] = 0;
  __syncthreads();
  int flag = fl[n];
  unsigned long long m = __ballot(flag);
  int lane = n & 63, w = n >> 6;
  int pre = __popcll(m & ((1ULL << lane) - 1ULL));
  if (lane == 63) wsum[w] = pre + flag;
  __syncthreads();
  int off = 0;
  #pragma unroll
  for (int i = 0; i < 16; ++i) off += (i < w) ? wsum[i] : 0;
  if (n < NN) {
    if (flag) {
      int j = off + pre;
      unselect[b*800 + j] = n;
      pos[b*NN + n] = j + 1;
    } else {
      pos[b*NN + n] = -1;
    }
  }
}

// ---------------- X ends: rows 0 and LQ-1 (matvec) ----------------
__global__ __launch_bounds__(128) void k_embed_ends(const float* __restrict__ data,
                       const int* __restrict__ sel,
                       const float* __restrict__ Wfirst, const float* __restrict__ bfirst,
                       const float* __restrict__ Wlast, const float* __restrict__ blast,
                       float* __restrict__ X, unsigned short* __restrict__ Xbf) {
  int which = blockIdx.x, b = blockIdx.y, d = threadIdx.x;
  int l = (which == 0) ? 0 : LQ-1;
  __shared__ float xr[DD];
  int src = sel[b*SS + (which == 0 ? 0 : SS-1)];
  const float* W    = (which == 0) ? Wfirst : Wlast;
  const float* bias = (which == 0) ? bfirst : blast;
  xr[d] = data[((size_t)b*NN + src)*DD + d];
  __syncthreads();
  float acc = bias[d];
  #pragma unroll 4
  for (int k = 0; k < DD; ++k) acc += xr[k] * W[k*DD + d];
  size_t off = ((size_t)(b*LQ + l))*DD + d;
  X[off] = acc;
  Xbf[off] = f2bf1(acc);
}

// ---------------- X middle: gather rows, float4 ----------------
__global__ __launch_bounds__(256) void k_embed_mid(const float* __restrict__ data,
                       const int* __restrict__ unselect,
                       float* __restrict__ X, unsigned short* __restrict__ Xbf) {
  int e = blockIdx.x*256 + threadIdx.x;      // 819200 total
  int r = e >> 5;                            // 0..25599
  int c4 = (e & 31) * 4;
  int b = r / 800, j = r - b*800;
  int nidx = unselect[r];
  const float4 v = *(const float4*)&data[((size_t)b*NN + nidx)*DD + c4];
  size_t off = ((size_t)(b*LQ + 1 + j))*DD + c4;
  *(float4*)&X[off] = v;
  unsigned int lo = cvtpk_bf16(v.x, v.y);
  unsigned int hi = cvtpk_bf16(v.z, v.w);
  unsigned long long pk8 = ((unsigned long long)hi << 32) | (unsigned long long)lo;
  *(unsigned long long*)&Xbf[off] = pk8;
}

// ---------------- MFMA QKV: C[M x 384] = Xbf @ [Wq|Wk|Wv]; row-major Q/K/V [bh][LPAD][dk] ----------------
// Q is pre-scaled by 0.25*log2e so attention softmax runs in exp2 units.
__global__ __launch_bounds__(256) void k_qkv_mfma(const unsigned short* __restrict__ Xbf,
                       const unsigned short* __restrict__ Wt,   // [384][128]
                       unsigned short* __restrict__ Qb, unsigned short* __restrict__ Kb,
                       unsigned short* __restrict__ Vb) {
  int row0 = blockIdx.x * 64;
  int t = threadIdx.x, wave = t >> 6, lane = t & 63;
  int col = lane & 31, half = lane >> 5;
  // batch-split trick: a 64-row block crosses at most one batch boundary
  int b0 = row0 / LQ;
  int l00 = row0 - b0*LQ;
  int split = LQ - l00;          // ml < split -> batch b0 at row l00+ml; else b0+1 at ml-split
  short8 a[2][8];
  const unsigned short* xb = Xbf + (size_t)(row0 + col)*DD + half*8;
  #pragma unroll
  for (int mi = 0; mi < 2; ++mi)
    #pragma unroll
    for (int s = 0; s < 8; ++s)
      a[mi][s] = *(const short8*)(xb + (size_t)mi*32*DD + s*16);
  #pragma unroll
  for (int nn = 0; nn < 3; ++nn) {
    int ni = wave*3 + nn;
    short8 bfr[8];
    const unsigned short* wb = Wt + (size_t)(ni*32 + col)*DD + half*8;
    #pragma unroll
    for (int s = 0; s < 8; ++s) bfr[s] = *(const short8*)(wb + s*16);
    f32x16 acc0 = {0.f,0.f,0.f,0.f,0.f,0.f,0.f,0.f,0.f,0.f,0.f,0.f,0.f,0.f,0.f,0.f};
    f32x16 acc1 = {0.f,0.f,0.f,0.f,0.f,0.f,0.f,0.f,0.f,0.f,0.f,0.f,0.f,0.f,0.f,0.f};
    #pragma unroll
    for (int s = 0; s < 8; ++s) {
      acc0 = __builtin_amdgcn_mfma_f32_32x32x16_bf16(a[0][s], bfr[s], acc0, 0, 0, 0);
      acc1 = __builtin_amdgcn_mfma_f32_32x32x16_bf16(a[1][s], bfr[s], acc1, 0, 0, 0);
    }
    int n = ni*32 + col;
    int sect = n >> 7, nc = n & 127;
    int h = nc >> 4, d = nc & 15;
    #pragma unroll
    for (int mi = 0; mi < 2; ++mi) {
      const f32x16& acc = mi ? acc1 : acc0;
      #pragma unroll
      for (int r = 0; r < 16; ++r) {
        int ml = mi*32 + (r&3) + 8*(r>>2) + 4*half;
        int over = (ml >= split);
        int b_ = b0 + over;
        int l  = over ? (ml - split) : (l00 + ml);
        size_t bh = (size_t)(b_*HH + h);
        float v = acc[r];
        if (sect == 0)      Qb[(bh*LPAD + l)*DKK + d] = f2bf1(v * QSCALE);
        else if (sect == 1) Kb[(bh*LPAD + l)*DKK + d] = f2bf1(v);
        else                Vb[(bh*LPAD + l)*DKK + d] = f2bf1(v);
      }
    }
  }
}

// ---------------- V transpose (LDS-tiled) + zero pads of Vt and Kb ----------------
__global__ __launch_bounds__(256) void k_vt(const unsigned short* __restrict__ Vb,  // [bh][LPAD][16]
                                            unsigned short* __restrict__ Vt,        // [bh][16][LPAD]
                                            unsigned short* __restrict__ Kb) {
  __shared__ unsigned short Lt[16][72];
  int l0 = blockIdx.x * 64;                 // 13 tiles cover 832
  int bh = blockIdx.y;
  int t = threadIdx.x;
  int l = t >> 2, d4 = (t & 3) * 4;
  ushort4 v = {0,0,0,0};
  if (l0 + l < LQ) v = *(const ushort4*)&Vb[((size_t)bh*LPAD + l0 + l)*DKK + d4];
  Lt[d4+0][l] = v.x; Lt[d4+1][l] = v.y; Lt[d4+2][l] = v.z; Lt[d4+3][l] = v.w;
  __syncthreads();
  int dk = t >> 4, lq = (t & 15)*4;
  ushort4 o;
  o.x = Lt[dk][lq]; o.y = Lt[dk][lq+1]; o.z = Lt[dk][lq+2]; o.w = Lt[dk][lq+3];
  *(ushort4*)&Vt[((size_t)bh*DKK + dk)*LPAD + l0 + lq] = o;
  if (blockIdx.x == 12 && t < 240)          // zero Kb pad rows (30 rows * 16 dk = 240 uints)
    ((unsigned int*)&Kb[((size_t)bh*LPAD + LQ)*DKK])[t] = 0u;
}

// ---------------- flash attention, 64 queries/block, S^T = K·Q^T, padded keys ----------------
// Offset-free softmax: O = PV/S is invariant to any per-q scale of P, so p = 2^c raw
// (no max subtraction on the common path). The max tree survives only as an overflow guard:
// if a tile max would push p past 2^80, fall back to the pair-consistent rescale path
// (wave-uniform 'act' switches to the c-runm form; exact for arbitrary scores).
// Denominator via MFMA: lanes col==16 carry a bf16-ones V-row, so oacc[8] (half-0) =
// sum_k p~[k] per query -- numerator and denominator use the SAME bf16 p (consistent
// convex combination). Pads contribute exactly bf16(2^0)=1 each, removed analytically.
__global__ __launch_bounds__(256) void k_attn3(const unsigned short* __restrict__ Q,
                       const unsigned short* __restrict__ K,
                       const unsigned short* __restrict__ Vt,
                       unsigned short* __restrict__ Obf) {
  int bid = blockIdx.x;
  int g = bid & 7, i = bid >> 3;            // XCD swizzle
  int bhg = i / NQT64, qt = i - bhg*NQT64;
  int bh = bhg*8 + g;
  int b = bh >> 3, h = bh & 7;
  int q0 = qt*64;
  size_t bhL = (size_t)bh * LPAD;
  int t = threadIdx.x;
  int wave = t >> 6, lane = t & 63;
  int col = lane & 31;
  int half = lane >> 5;

  __shared__ float mw[2][4][32];
  __shared__ float sw[2][4][32];
  __shared__ float sfin[2][32];
  __shared__ float ored[2][4][16][32];      // 16 KB
  __shared__ float osum[2][32][17];

  // direction probe: case1 <=> new D.lo = S.hi
  uint2v pr = pls(1000u + (unsigned)lane, 2000u + (unsigned)lane);
  bool case1 = (__builtin_amdgcn_readfirstlane((int)pr.x) >= 2000);

  int q0c = q0 + col;      if (q0c > LQ-1) q0c = LQ-1;
  int q1c = q0 + 32 + col; if (q1c > LQ-1) q1c = LQ-1;
  short8 bQ0 = *(const short8*)&Q[(bhL + q0c)*DKK + half*8];
  short8 bQ1 = *(const short8*)&Q[(bhL + q1c)*DKK + half*8];

  f32x16 oacc0 = {0.f,0.f,0.f,0.f,0.f,0.f,0.f,0.f,0.f,0.f,0.f,0.f,0.f,0.f,0.f,0.f};
  f32x16 oacc1 = oacc0;
  float runm0 = 0.f, runm1 = 0.f;           // offsets; stay 0 unless guard fires
  bool act = false;                         // wave-uniform: any rescale happened

  // V fragments: col<16 loaded per tile; col==16 holds bf16 ones (denominator row d=16);
  // col>16 stays zero. Exec-masked loads leave non-participating lanes' values intact.
  short8 aV0 = {0,0,0,0,0,0,0,0};
  short8 aV1 = {0,0,0,0,0,0,0,0};
  if (col == 16) {
    union { unsigned int u[4]; short8 s8; } o;
    o.u[0] = o.u[1] = o.u[2] = o.u[3] = 0x3F803F80u;
    aV0 = o.s8; aV1 = o.s8;
  }

  for (int kt = wave; kt < NQT; kt += 4) {
    int key0 = kt*32;
    short8 aK = *(const short8*)&K[(bhL + key0 + col)*DKK + half*8];
    if (col < 16) {
      const unsigned short* vp = &Vt[((size_t)bh*DKK + col)*LPAD + key0 + half*8];
      aV0 = *(const short8*)vp;
      aV1 = *(const short8*)(vp + 16);
    }

    auto process = [&](const short8& bQ, f32x16& oacc, float& runm) {
      f32x16 c = {0.f,0.f,0.f,0.f,0.f,0.f,0.f,0.f,0.f,0.f,0.f,0.f,0.f,0.f,0.f,0.f};
      c = __builtin_amdgcn_mfma_f32_32x32x16_bf16(aK, bQ, c, 0, 0, 0);
      // tile max (overflow guard only)
      float m0 = max3f(c[0],  c[1],  c[2]);
      float m1 = max3f(c[3],  c[4],  c[5]);
      float m2 = max3f(c[6],  c[7],  c[8]);
      float m3 = max3f(c[9],  c[10], c[11]);
      float m4 = max3f(c[12], c[13], c[14]);
      float tm = fmaxf(max3f(m0, m1, m2), max3f(m3, m4, c[15]));
      if (!__all(tm <= runm + 80.0f)) {     // rare: p would exceed 2^80
        uint2v rr = pls(fu(tm), fu(tm));
        float tmp = max3f(tm, uf(rr.x), uf(rr.y));   // pair-consistent tile max
        float mnew = fmaxf(runm, tmp);
        float sc = exp2n(runm - mnew);
        #pragma unroll
        for (int r = 0; r < 9; ++r) oacc[r] *= sc;   // include denominator row r=8
        runm = mnew;
        act = true;
      }
      float p[16];
      if (act) {
        #pragma unroll
        for (int r = 0; r < 16; ++r) p[r] = exp2n(c[r] - runm);
      } else {
        #pragma unroll
        for (int r = 0; r < 16; ++r) p[r] = exp2n(c[r]);   // common path: no subtract
      }
      unsigned int pk[8];
      #pragma unroll
      for (int j = 0; j < 8; ++j) pk[j] = cvtpk_bf16(p[2*j], p[2*j+1]);
      unsigned int fAx, fAy, fAz, fAw, fBx, fBy, fBz, fBw;
      if (case1) {
        uint2v r0 = pls(pk[2], pk[0]); fAz = r0.x; fAx = r0.y;
        uint2v r1 = pls(pk[3], pk[1]); fAw = r1.x; fAy = r1.y;
        uint2v r2 = pls(pk[6], pk[4]); fBz = r2.x; fBx = r2.y;
        uint2v r3 = pls(pk[7], pk[5]); fBw = r3.x; fBy = r3.y;
      } else {
        uint2v r0 = pls(pk[0], pk[2]); fAx = r0.x; fAz = r0.y;
        uint2v r1 = pls(pk[1], pk[3]); fAy = r1.x; fAw = r1.y;
        uint2v r2 = pls(pk[4], pk[6]); fBx = r2.x; fBz = r2.y;
        uint2v r3 = pls(pk[5], pk[7]); fBy = r3.x; fBw = r3.y;
      }
      union { unsigned int u[4]; short8 s8; } fA, fB;
      fA.u[0] = fAx; fA.u[1] = fAy; fA.u[2] = fAz; fA.u[3] = fAw;
      fB.u[0] = fBx; fB.u[1] = fBy; fB.u[2] = fBz; fB.u[3] = fBw;
      oacc = __builtin_amdgcn_mfma_f32_32x32x16_bf16(aV0, fA.s8, oacc, 0, 0, 0);
      oacc = __builtin_amdgcn_mfma_f32_32x32x16_bf16(aV1, fB.s8, oacc, 0, 0, 0);
    };
    process(bQ0, oacc0, runm0);
    process(bQ1, oacc1, runm1);
  }

  // ---- stage per-wave offset + MFMA-computed denominator (row d=16 -> oacc[8], half-0) ----
  if (half == 0) {
    mw[0][wave][col] = runm0;  sw[0][wave][col] = oacc0[8];
    mw[1][wave][col] = runm1;  sw[1][wave][col] = oacc1[8];
  }
  __syncthreads();
  #pragma unroll
  for (int u = 0; u < 2; ++u) {
    float M = fmaxf(fmaxf(mw[u][0][col], mw[u][1][col]), fmaxf(mw[u][2][col], mw[u][3][col]));
    float S = sw[u][0][col]*exp2n(mw[u][0][col]-M) + sw[u][1][col]*exp2n(mw[u][1][col]-M)
            + sw[u][2][col]*exp2n(mw[u][2][col]-M) + sw[u][3][col]*exp2n(mw[u][3][col]-M);
    float runm = u ? runm1 : runm0;          // pair-consistent by construction
    float fw = exp2n(runm - M);
    const f32x16& oacc = u ? oacc1 : oacc0;
    #pragma unroll
    for (int r = 0; r < 8; ++r) {
      int dv = (r&3) + 8*(r>>2) + 4*half;
      ored[u][wave][dv][col] = oacc[r] * fw;
    }
    if (wave == 0 && half == 0)
      sfin[u][col] = S - (float)NPADK * exp2n(-M);   // remove exact pad mass
  }
  __syncthreads();
  {
    int qq = t & 31, dv0 = t >> 5;
    #pragma unroll
    for (int u = 0; u < 2; ++u)
      #pragma unroll
      for (int k = 0; k < 2; ++k) {
        int dv = dv0 + 8*k;
        osum[u][qq][dv] = ored[u][0][dv][qq] + ored[u][1][dv][qq]
                        + ored[u][2][dv][qq] + ored[u][3][dv][qq];
      }
  }
  __syncthreads();
  {
    int qs = t >> 3, c2 = (t & 7)*2;
    #pragma unroll
    for (int u = 0; u < 2; ++u) {
      int q = q0 + u*32 + qs;
      if (q < LQ) {
        float invS = 1.f / sfin[u][qs];
        unsigned int pkv = cvtpk_bf16(osum[u][qs][c2] * invS, osum[u][qs][c2+1] * invS);
        *(unsigned int*)&Obf[((size_t)(b*LQ + q))*DD + h*DKK + c2] = pkv;
      }
    }
  }
}

// ---------------- fused proj + FF: X = out1 + ff(out1), out1 = X + Obf@Wo + bo ----------------
__global__ __launch_bounds__(256) void k_pff(const unsigned short* __restrict__ Obf,
        const unsigned short* __restrict__ Wot, const float* __restrict__ bo,
        const unsigned short* __restrict__ W1t, const float* __restrict__ b1,
        const unsigned short* __restrict__ W2t, const float* __restrict__ b2,
        float* __restrict__ X, unsigned short* __restrict__ Xbf) {
  __shared__ __align__(16) unsigned short LDSU[64 * HSTR];   // 66048 B, union T/Hs
  unsigned short* T  = LDSU;
  unsigned short* Hs = LDSU;
  int row0 = blockIdx.x * 64;
  int t = threadIdx.x, wave = t >> 6, lane = t & 63;
  int col = lane & 31, half = lane >> 5;
  int n = wave*32 + col;
  float res[2][16];
  {
    short8 a[2][8];
    const unsigned short* ob = Obf + (size_t)(row0 + col)*DD + half*8;
    #pragma unroll
    for (int mi = 0; mi < 2; ++mi)
      #pragma unroll
      for (int s = 0; s < 8; ++s)
        a[mi][s] = *(const short8*)(ob + (size_t)mi*32*DD + s*16);
    short8 bfr[8];
    const unsigned short* wb = Wot + (size_t)n*DD + half*8;
    #pragma unroll
    for (int s = 0; s < 8; ++s) bfr[s] = *(const short8*)(wb + s*16);
    f32x16 acc0 = {0.f,0.f,0.f,0.f,0.f,0.f,0.f,0.f,0.f,0.f,0.f,0.f,0.f,0.f,0.f,0.f};
    f32x16 acc1 = acc0;
    #pragma unroll
    for (int s = 0; s < 8; ++s) {
      acc0 = __builtin_amdgcn_mfma_f32_32x32x16_bf16(a[0][s], bfr[s], acc0, 0, 0, 0);
      acc1 = __builtin_amdgcn_mfma_f32_32x32x16_bf16(a[1][s], bfr[s], acc1, 0, 0, 0);
    }
    float bv = bo[n];
    #pragma unroll
    for (int mi = 0; mi < 2; ++mi) {
      const f32x16& acc = mi ? acc1 : acc0;
      #pragma unroll
      for (int r = 0; r < 16; ++r) {
        int ml = mi*32 + (r&3) + 8*(r>>2) + 4*half;
        size_t off = (size_t)(row0 + ml)*DD + n;
        res[mi][r] = X[off] + acc[r] + bv;
        T[ml*TSTR + n] = f2bf1(res[mi][r]);
      }
    }
  }
  __syncthreads();
  short8 aF[2][8];
  #pragma unroll
  for (int mi = 0; mi < 2; ++mi)
    #pragma unroll
    for (int s = 0; s < 8; ++s) {
      const unsigned short* tp = &T[(mi*32 + col)*TSTR + half*8 + s*16];
      union { short4v h[2]; short8 v; } u;
      u.h[0] = *(const short4v*)tp;
      u.h[1] = *(const short4v*)(tp + 4);
      aF[mi][s] = u.v;
    }
  __syncthreads();
  #pragma unroll
  for (int nn = 0; nn < 4; ++nn) {
    int ni = wave*4 + nn;
    short8 bfr[8];
    const unsigned short* wb = W1t + (size_t)(ni*32 + col)*DD + half*8;
    #pragma unroll
    for (int s = 0; s < 8; ++s) bfr[s] = *(const short8*)(wb + s*16);
    f32x16 acc0 = {0.f,0.f,0.f,0.f,0.f,0.f,0.f,0.f,0.f,0.f,0.f,0.f,0.f,0.f,0.f,0.f};
    f32x16 acc1 = acc0;
    #pragma unroll
    for (int s = 0; s < 8; ++s) {
      acc0 = __builtin_amdgcn_mfma_f32_32x32x16_bf16(aF[0][s], bfr[s], acc0, 0, 0, 0);
      acc1 = __builtin_amdgcn_mfma_f32_32x32x16_bf16(aF[1][s], bfr[s], acc1, 0, 0, 0);
    }
    int nf = ni*32 + col;
    float bv = b1[nf];
    #pragma unroll
    for (int mi = 0; mi < 2; ++mi) {
      const f32x16& acc = mi ? acc1 : acc0;
      #pragma unroll
      for (int r = 0; r < 16; ++r) {
        int ml = mi*32 + (r&3) + 8*(r>>2) + 4*half;
        Hs[ml*HSTR + nf] = f2bf1(fmaxf(acc[r] + bv, 0.f));
      }
    }
  }
  __syncthreads();
  f32x16 acc0 = {0.f,0.f,0.f,0.f,0.f,0.f,0.f,0.f,0.f,0.f,0.f,0.f,0.f,0.f,0.f,0.f};
  f32x16 acc1 = acc0;
  const unsigned short* w2b = W2t + (size_t)n*FFD + half*8;
  #pragma unroll 4
  for (int s = 0; s < 32; ++s) {
    int ko = s*16 + half*8;
    union { short4v h[2]; short8 v; } h0, h1;
    const unsigned short* hp0 = &Hs[col*HSTR + ko];
    const unsigned short* hp1 = &Hs[(32 + col)*HSTR + ko];
    h0.h[0] = *(const short4v*)hp0;  h0.h[1] = *(const short4v*)(hp0 + 4);
    h1.h[0] = *(const short4v*)hp1;  h1.h[1] = *(const short4v*)(hp1 + 4);
    short8 bfr = *(const short8*)(w2b + s*16);
    acc0 = __builtin_amdgcn_mfma_f32_32x32x16_bf16(h0.v, bfr, acc0, 0, 0, 0);
    acc1 = __builtin_amdgcn_mfma_f32_32x32x16_bf16(h1.v, bfr, acc1, 0, 0, 0);
  }
  float bv = b2[n];
  #pragma unroll
  for (int mi = 0; mi < 2; ++mi) {
    const f32x16& acc = mi ? acc1 : acc0;
    #pragma unroll
    for (int r = 0; r < 16; ++r) {
      int ml = mi*32 + (r&3) + 8*(r>>2) + 4*half;
      size_t off = (size_t)(row0 + ml)*DD + n;
      float v = res[mi][r] + acc[r] + bv;
      X[off] = v;
      Xbf[off] = f2bf1(v);
    }
  }
}

// ---------------- logits: one wave per row ----------------
__global__ __launch_bounds__(256) void k_logits(const float* __restrict__ X,
                        const float* __restrict__ Wfin, const float* __restrict__ bfin,
                        float* __restrict__ logits) {
  int t = threadIdx.x, wave = t >> 6, lane = t & 63;
  int row = blockIdx.x*4 + wave;            // 6416*4 = 25664 exact
  float2 xv = *(const float2*)&X[(size_t)row*DD + lane*2];
  float2 wv = *(const float2*)&Wfin[lane*2];
  float v = xv.x*wv.x + xv.y*wv.y;
  #pragma unroll
  for (int off = 32; off > 0; off >>= 1) v += __shfl_down(v, off);
  if (lane == 0) logits[row] = v + bfin[0];
}

// ---------------- bias add, softmax, epsilon, scatter ----------------
__global__ __launch_bounds__(256) void k_final(const float* __restrict__ logits,
                       const float* __restrict__ AB, const int* __restrict__ sel,
                       const int* __restrict__ unselect, const int* __restrict__ pos,
                       float* __restrict__ out) {
  int b = blockIdx.x, t = threadIdx.x;
  __shared__ float sl[800];
  __shared__ float red[256];
  int lastsel = sel[b*SS + SS-1];
  const float* abrow = AB + ((size_t)b*NN + lastsel)*NN;
  for (int j = t; j < 800; j += 256)
    sl[j] = logits[b*LQ + j + 1] + abrow[unselect[b*800 + j]];
  __syncthreads();
  float lm = -INFINITY;
  for (int j = t; j < 800; j += 256) lm = fmaxf(lm, sl[j]);
  red[t] = lm;
  __syncthreads();
  for (int s = 128; s > 0; s >>= 1) {
    if (t < s) red[t] = fmaxf(red[t], red[t+s]);
    __syncthreads();
  }
  float m = red[0];
  __syncthreads();
  float ls = 0.f;
  for (int j = t; j < 800; j += 256) ls += __expf(sl[j] - m);
  red[t] = ls;
  __syncthreads();
  for (int s = 128; s > 0; s >>= 1) {
    if (t < s) red[t] += red[t+s];
    __syncthreads();
  }
  float inv = 1.f / red[0];
  for (int n = t; n < NN; n += 256) {
    int p1 = pos[b*NN + n];
    float v = -2.0f;
    if (p1 >= 0) {
      float p = __expf(sl[p1-1] - m) * inv;
      if (p <= 1e-5f) p += 1e-7f;
      v = p;
    }
    out[(size_t)b*NN + n] = v;
  }
}

extern "C" void kernel_launch(void* const* d_in, const int* in_sizes, int n_in,
                              void* d_out, int out_size, void* d_ws, size_t ws_size,
                              hipStream_t stream) {
  const float* data   = (const float*)d_in[0];
  const float* AB     = (const float*)d_in[1];
  const float* Wfirst = (const float*)d_in[2];
  const float* bfirst = (const float*)d_in[3];
  const float* Wlast  = (const float*)d_in[4];
  const float* blast  = (const float*)d_in[5];
  const float* Wq     = (const float*)d_in[6];
  const float* Wk     = (const float*)d_in[7];
  const float* Wv     = (const float*)d_in[8];
  const float* Wo     = (const float*)d_in[9];
  const float* bo     = (const float*)d_in[10];
  const float* W1     = (const float*)d_in[11];
  const float* b1     = (const float*)d_in[12];
  const float* W2     = (const float*)d_in[13];
  const float* b2     = (const float*)d_in[14];
  const float* Wfin   = (const float*)d_in[15];
  const float* bfin   = (const float*)d_in[16];
  const int*   sel    = (const int*)d_in[17];
  float* out = (float*)d_out;
  (void)in_sizes; (void)n_in; (void)out_size; (void)ws_size;

  char* ws = (char*)d_ws;
  const size_t NELT = (size_t)MROWS * DD;        // 3,284,992
  const size_t KVELT = (size_t)NB*HH*LPAD*DKK;   // 3,407,872
  int*   UNSEL = (int*)ws;
  int*   POS   = (int*)(ws + 102400);
  float* X     = (float*)(ws + 230400);
  unsigned short* Xbf = (unsigned short*)(X + NELT);
  unsigned short* Ob  = Xbf + NELT;
  unsigned short* Qb  = Ob + NELT;
  unsigned short* Kb  = Qb + KVELT;
  unsigned short* Vb  = Kb + KVELT;
  unsigned short* Vt  = Vb + KVELT;
  unsigned short* WtQKV = Vt + KVELT;
  unsigned short* Wot = WtQKV + (size_t)NLAYER*384*128;
  unsigned short* W1t = Wot + (size_t)NLAYER*128*128;
  unsigned short* W2t = W1t + (size_t)NLAYER*512*128;
  float* LOG = (float*)(W2t + (size_t)NLAYER*128*512);

  k_wconv<<<(3*WCH + 255)/256, 256, 0, stream>>>(Wq, Wk, Wv, Wo, W1, W2, WtQKV, Wot, W1t, W2t);
  k_unselect<<<NB, 1024, 0, stream>>>(sel, UNSEL, POS);
  k_embed_ends<<<dim3(2, NB), 128, 0, stream>>>(data, sel, Wfirst, bfirst, Wlast, blast, X, Xbf);
  k_embed_mid<<<3200, 256, 0, stream>>>(data, UNSEL, X, Xbf);
  for (int i = 0; i < NLAYER; ++i) {
    k_qkv_mfma<<<NBLK64, 256, 0, stream>>>(Xbf, WtQKV + (size_t)i*384*128, Qb, Kb, Vb);
    k_vt<<<dim3(13, NB*HH), 256, 0, stream>>>(Vb, Vt, Kb);
    k_attn3<<<NQT64*HH*NB, 256, 0, stream>>>(Qb, Kb, Vt, Ob);
    k_pff<<<NBLK64, 256, 0, stream>>>(Ob, Wot + (size_t)i*128*128, bo + (size_t)i*DD,
                                      W1t + (size_t)i*512*128, b1 + (size_t)i*FFD,
                                      W2t + (size_t)i*128*512, b2 + (size_t)i*DD, X, Xbf);
  }
  k_logits<<<MROWS/4, 256, 0, stream>>>(X, Wfin, bfin, LOG);
  k_final<<<NB, 256, 0, stream>>>(LOG, AB, sel, UNSEL, POS, out);
}